// Round 9
// baseline (187.233 us; speedup 1.0000x reference)
//
#include <hip/hip_runtime.h>

#define DF 128     // feature dim
#define KX 256     // extended GEMM K: [Agg | feat]
#define CAP 16     // bucket capacity per node = one 64B cache line
#define GR 64      // GEMM rows per block

typedef __attribute__((ext_vector_type(8))) short short8;   // 8 bf16 (4 VGPRs)
typedef __attribute__((ext_vector_type(4))) float v4f;      // MFMA accumulator
typedef __attribute__((ext_vector_type(4))) float f32x4;    // for nt loads

__device__ __forceinline__ unsigned short f2bf(float x) {
    unsigned u = __float_as_uint(x);
    unsigned r = (u + 0x7FFFu + ((u >> 16) & 1u)) >> 16;    // RNE
    return (unsigned short)r;
}
__device__ __forceinline__ float bf2f(unsigned short h) {
    return __uint_as_float((unsigned)h << 16);
}
__device__ __forceinline__ unsigned pack2(float a, float b) {
    return (unsigned)f2bf(a) | ((unsigned)f2bf(b) << 16);
}

// 16B-unit XOR swizzle for the 32KB A tile
#define ASW(r, u) (((r) << 5) + ((u) ^ ((r) & 7)))

__device__ __forceinline__ bool detect_is32(const void* src, int nE, int t) {
    // int32 input -> sampled odd 32-bit words are real node ids (nonzero
    // w.h.p. over 512 samples); int64 -> hi words are 0.
    const int* p32 = (const int*)src;
    const int s0 = (t < nE) ? t : 0;
    const int s1 = (t + 256 < nE) ? t + 256 : 0;
    const int pred = (p32[2 * s0 + 1] | p32[2 * s1 + 1]) != 0;
    return (__ballot(pred) != 0ull);
}

// ---------------------------------------------------------------------------
// mega: one dispatch fusing three independent jobs, roles STRIPED across
// blockIdx so latency-bound placement and BW-bound conversion co-reside.
// Single-use streams (edge lists, feat) use NONTEMPORAL loads so the
// cache space stays available for buckets/counts/Fbf (reused by agg).
// Requires counts==0 and hdr[1]==0 on entry (per-call memset — workspace is
// re-poisoned between calls).
// ---------------------------------------------------------------------------
__global__ __launch_bounds__(256) void mega_kernel(
    const void* __restrict__ src, const void* __restrict__ dst, int nE,
    int* __restrict__ hdr, int* __restrict__ counts, int* __restrict__ buckets,
    int2* __restrict__ ovf,
    const float* __restrict__ Wn, const float* __restrict__ Ws,
    unsigned short* __restrict__ Bt2,
    const float* __restrict__ feat, unsigned short* __restrict__ Fbf,
    int M, int NPB, int kstripe)
{
    const int b = blockIdx.x;
    const int t = threadIdx.x;

    // ---- role decode: placement striped at every kstripe-th index ----
    int pid = -1, j = 0;
    {
        const int q = b / kstripe;
        if ((b % kstripe) == 0 && q < NPB) {
            pid = q;                                   // placement block id
        } else {
            const int placed_before = min(NPB, q + ((b % kstripe) ? 1 : 0));
            j = b - placed_before;                     // non-place job id
        }
    }

    if (pid >= 0) {
        // ---------------- placement: 1 edge per thread ----------------
        const bool is32 = detect_is32(src, nE, t);
        const int e = pid * 256 + t;
        if (e < nE) {
            int s, d;
            if (is32) {
                s = __builtin_nontemporal_load((const int*)src + e);
                d = __builtin_nontemporal_load((const int*)dst + e);
            } else {
                s = (int)__builtin_nontemporal_load((const long long*)src + e);
                d = (int)__builtin_nontemporal_load((const long long*)dst + e);
            }
            int pos = atomicAdd(&counts[d], 1);
            if (pos < CAP) {
                buckets[(size_t)d * CAP + pos] = s;
            } else {
                int oi = atomicAdd(&hdr[1], 1);
                ovf[oi] = make_int2(s, d);
            }
        }
    } else if (j < 128) {
        // ---------------- Bt2 build: [n][k], k<128 -> Wn, else Ws ----------
        int idx = j * 256 + t;              // 0..32767 over [n][k]
        int n = idx >> 8, k = idx & 255;
        float v = (k < DF) ? Wn[(size_t)k * DF + n]
                           : Ws[(size_t)(k - DF) * DF + n];
        Bt2[idx] = f2bf(v);
    } else {
        // ---------------- feat -> bf16 (+ zero sentinel row M) -------------
        const long long base = ((long long)(j - 128) * 2048 + t * 8);
        const long long mtot = (long long)M * DF;
        const long long ttot = (long long)(M + 1) * DF;
        if (base + 8 <= mtot) {
            f32x4 v0 = __builtin_nontemporal_load(
                reinterpret_cast<const f32x4*>(feat + base));
            f32x4 v1 = __builtin_nontemporal_load(
                reinterpret_cast<const f32x4*>(feat + base + 4));
            uint4 pk;
            pk.x = pack2(v0.x, v0.y);
            pk.y = pack2(v0.z, v0.w);
            pk.z = pack2(v1.x, v1.y);
            pk.w = pack2(v1.z, v1.w);
            *reinterpret_cast<uint4*>(Fbf + base) = pk;
        } else if (base + 8 <= ttot) {
            *reinterpret_cast<uint4*>(Fbf + base) = make_uint4(0u, 0u, 0u, 0u);
        }
    }
}

// ---------------------------------------------------------------------------
// agg_gemm: per 64-node tile, (1) aggregate neighbor Fbf rows (branch-free
// sentinel bursts, f32 accum) + stage self row -> swizzled As (32KB),
// (2) K=256 MFMA: out = [Agg|feat] @ [Wn;Ws] + b, written ONCE with
// NONTEMPORAL stores (out is never re-read; plain stores were evicting the
// L3-resident Fbf working set and inflating FETCH to 81.6MB vs ~35 ideal).
// ---------------------------------------------------------------------------
__global__ __launch_bounds__(256) void agg_gemm_kernel(
    const unsigned short* __restrict__ Fbf, const unsigned short* __restrict__ Bt2,
    const float* __restrict__ bias, float* __restrict__ out, int M,
    const int* __restrict__ counts, const int* __restrict__ buckets,
    const int* __restrict__ hdr, const int2* __restrict__ ovf)
{
    __shared__ uint4 As16[GR * 32];   // 64 rows x 32 x 16B = 32 KB, swizzled

    const int t = threadIdx.x;
    const int block_row = blockIdx.x * GR;

    const int wave = t >> 6;
    const int lane = t & 63;
    const int nl   = lane & 15;
    const int quad = lane >> 4;

    // ---- preload B fragments (independent, L2-hot, arrive under agg) ----
    const int n0 = wave * 32;
    short8 bfrag[2][8];
#pragma unroll
    for (int ct = 0; ct < 2; ct++)
#pragma unroll
        for (int kk = 0; kk < 8; kk++)
            bfrag[ct][kk] = *reinterpret_cast<const short8*>(
                Bt2 + (size_t)(n0 + ct * 16 + nl) * KX + kk * 32 + quad * 8);
    float bcol[2];
#pragma unroll
    for (int ct = 0; ct < 2; ct++)
        bcol[ct] = bias[n0 + ct * 16 + nl];

    // ---- phase 1: aggregate 4 nodes per 16-lane group ----
    {
        const int gi = t >> 4;
        const int li = t & 15;
        const size_t lo = (size_t)li * 8;
        const int n_ovf = hdr[1];

#define LDF(s) (*reinterpret_cast<const uint4*>(Fbf + (size_t)(s) * DF + lo))
#define ACC8(Y) do { \
        a0 += bf2f((unsigned short)((Y).x)); a1 += bf2f((unsigned short)((Y).x >> 16)); \
        a2 += bf2f((unsigned short)((Y).y)); a3 += bf2f((unsigned short)((Y).y >> 16)); \
        a4 += bf2f((unsigned short)((Y).z)); a5 += bf2f((unsigned short)((Y).z >> 16)); \
        a6 += bf2f((unsigned short)((Y).w)); a7 += bf2f((unsigned short)((Y).w >> 16)); \
    } while (0)

#pragma unroll
        for (int j = 0; j < 4; j++) {
            const int r_local = gi * 4 + j;
            const int grow = block_row + r_local;
            const int deg_raw = (grow < M) ? counts[grow] : 0;
            const int deg = min(deg_raw, CAP);
            const int* b = buckets + (size_t)((grow < M) ? grow : 0) * CAP;

            float a0 = 0.f, a1 = 0.f, a2 = 0.f, a3 = 0.f;
            float a4 = 0.f, a5 = 0.f, a6 = 0.f, a7 = 0.f;

            int4 sa = *reinterpret_cast<const int4*>(b);
            int4 sb = *reinterpret_cast<const int4*>(b + 4);
            const int i0 = (0 < deg) ? sa.x : M;
            const int i1 = (1 < deg) ? sa.y : M;
            const int i2 = (2 < deg) ? sa.z : M;
            const int i3 = (3 < deg) ? sa.w : M;
            const int i4 = (4 < deg) ? sb.x : M;
            const int i5 = (5 < deg) ? sb.y : M;
            const int i6 = (6 < deg) ? sb.z : M;
            const int i7 = (7 < deg) ? sb.w : M;
            uint4 y0 = LDF(i0);
            uint4 y1 = LDF(i1);
            uint4 y2 = LDF(i2);
            uint4 y3 = LDF(i3);
            uint4 y4 = LDF(i4);
            uint4 y5 = LDF(i5);
            uint4 y6 = LDF(i6);
            uint4 y7 = LDF(i7);
            uint4 sf = LDF((grow < M) ? grow : M);
            ACC8(y0); ACC8(y1); ACC8(y2); ACC8(y3);
            ACC8(y4); ACC8(y5); ACC8(y6); ACC8(y7);

            if (deg > 8) {
                int4 sc = *reinterpret_cast<const int4*>(b + 8);
                int4 sd = *reinterpret_cast<const int4*>(b + 12);
                const int j0 = ( 8 < deg) ? sc.x : M;
                const int j1 = ( 9 < deg) ? sc.y : M;
                const int j2 = (10 < deg) ? sc.z : M;
                const int j3 = (11 < deg) ? sc.w : M;
                const int j4 = (12 < deg) ? sd.x : M;
                const int j5 = (13 < deg) ? sd.y : M;
                const int j6 = (14 < deg) ? sd.z : M;
                const int j7 = (15 < deg) ? sd.w : M;
                uint4 z0 = LDF(j0);
                uint4 z1 = LDF(j1);
                uint4 z2 = LDF(j2);
                uint4 z3 = LDF(j3);
                uint4 z4 = LDF(j4);
                uint4 z5 = LDF(j5);
                uint4 z6 = LDF(j6);
                uint4 z7 = LDF(j7);
                ACC8(z0); ACC8(z1); ACC8(z2); ACC8(z3);
                ACC8(z4); ACC8(z5); ACC8(z6); ACC8(z7);
            }

            if (deg_raw > CAP) {   // rare overflow edges for this node
                for (int i = 0; i < n_ovf; i++) {
                    int2 sd2 = ovf[i];
                    if (sd2.y == grow) {
                        uint4 y = LDF(sd2.x);
                        ACC8(y);
                    }
                }
            }

            uint4 pk;
            pk.x = pack2(a0, a1);
            pk.y = pack2(a2, a3);
            pk.z = pack2(a4, a5);
            pk.w = pack2(a6, a7);
            As16[ASW(r_local, li)]      = pk;   // Agg half
            As16[ASW(r_local, 16 + li)] = sf;   // self half
        }
#undef LDF
#undef ACC8
    }

    __syncthreads();

    // ---- phase 2: K=256 MFMA, nontemporal out store (write-once) ----
#pragma unroll
    for (int rt = 0; rt < 4; rt++) {
        const int arow = rt * 16 + nl;
        short8 afrag[8];
#pragma unroll
        for (int kk = 0; kk < 8; kk++)
            afrag[kk] = *reinterpret_cast<const short8*>(
                &As16[ASW(arow, kk * 4 + quad)]);
#pragma unroll
        for (int ct = 0; ct < 2; ct++) {
            v4f acc = {0.f, 0.f, 0.f, 0.f};
#pragma unroll
            for (int kk = 0; kk < 8; kk++)
                acc = __builtin_amdgcn_mfma_f32_16x16x32_bf16(
                    afrag[kk], bfrag[ct][kk], acc, 0, 0, 0);
            const int n = n0 + ct * 16 + nl;
            const int lrow = rt * 16 + quad * 4;
#pragma unroll
            for (int r = 0; r < 4; r++) {
                const int grow = block_row + lrow + r;
                if (grow < M)
                    __builtin_nontemporal_store(
                        acc[r] + bcol[ct], out + (size_t)grow * DF + n);
            }
        }
    }
}

extern "C" void kernel_launch(void* const* d_in, const int* in_sizes, int n_in,
                              void* d_out, int out_size, void* d_ws, size_t ws_size,
                              hipStream_t stream) {
    const float* feat = (const float*)d_in[0];
    const void*  src  = d_in[1];
    const void*  dst  = d_in[2];
    const float* Wn   = (const float*)d_in[3];
    const float* bias = (const float*)d_in[4];
    const float* Wsf  = (const float*)d_in[5];
    float* out = (float*)d_out;

    const int M  = in_sizes[0] / DF;   // 100000
    const int nE = in_sizes[1];        // 600000

    // workspace: [hdr 256B][counts][buckets][Bt2 64KB][Fbf (M+1 rows)][ovf]
    const size_t cnt_off   = 256;
    const size_t cnt_bytes = (((size_t)(M + 64) * 4) + 255) & ~(size_t)255;
    const size_t bkt_off   = cnt_off + cnt_bytes;
    const size_t bkt_bytes = (size_t)M * CAP * sizeof(int);
    const size_t bt_off    = (bkt_off + bkt_bytes + 255) & ~(size_t)255;
    const size_t bt_bytes  = (size_t)DF * KX * sizeof(unsigned short);
    const size_t f_off     = bt_off + bt_bytes;
    const size_t f_bytes   = (size_t)(M + 1) * DF * sizeof(unsigned short);
    const size_t ovf_off   = (f_off + f_bytes + 255) & ~(size_t)255;

    int*            hdr     = (int*)d_ws;
    int*            counts  = (int*)((char*)d_ws + cnt_off);
    int*            buckets = (int*)((char*)d_ws + bkt_off);
    unsigned short* Bt2     = (unsigned short*)((char*)d_ws + bt_off);
    unsigned short* Fbf     = (unsigned short*)((char*)d_ws + f_off);
    int2*           ovf     = (int2*)((char*)d_ws + ovf_off);

    // per-call zero of hdr+counts (workspace is re-poisoned between calls)
    hipMemsetAsync(d_ws, 0, cnt_off + cnt_bytes, stream);

    const int NPB = (nE + 255) / 256;
    const long long ttot = (long long)(M + 1) * DF;
    const int nconv = (int)((ttot + 2047) / 2048);
    const int total = NPB + 128 + nconv;
    const int kstripe = total / NPB;   // >=1; stripes placement across grid

    mega_kernel<<<total, 256, 0, stream>>>(
        src, dst, nE, hdr, counts, buckets, ovf,
        Wn, Wsf, Bt2, feat, Fbf, M, NPB, kstripe);

    const int gemm_blocks = (M + GR - 1) / GR;
    agg_gemm_kernel<<<gemm_blocks, 256, 0, stream>>>(
        Fbf, Bt2, bias, out, M, counts, buckets, hdr, ovf);
}